// Round 1
// baseline (388.270 us; speedup 1.0000x reference)
//
#include <hip/hip_runtime.h>

// L1 loss between CIE-Lab L channels of two (64,3,512,512) f32 images.
//
// R3 theory: VGPR=32 in R2's "12-load straight-line" build proves the compiler
// serialized the loads (12 in-flight float4 need >=48 dest VGPRs). L3-resident
// replays at identical ~130us + VALUBusy 26% => latency-bound with effective
// MLP ~3/wave, delivering only 3.15 TB/s of a 6.3 TB/s ceiling.
// Fix: inline-asm global_load_dwordx4 into 12 distinct float4 outputs (forces
// >=48 live VGPRs -> hardware-guaranteed 12-deep MLP), consumed in two rounds
// via counted s_waitcnt vmcnt(6)/vmcnt(0) + sched_barrier(0) (rule #18).
// Also: thread t now handles groups t and t+2M (not 2t,2t+1), so every
// wave-load is a contiguous 1KB access (16 lines) instead of a 2KB span.

#define HW4   65536      // float4 groups per channel plane (512*512/4)
#define CHW4  196608     // 3*HW4 float4 groups per image
#define HALFG 2097152    // half of total groups (64*65536/2) = thread count
#define NPIX  16777216

__device__ __forceinline__ float fast_log2(float x) {
#if __has_builtin(__builtin_amdgcn_logf)
    return __builtin_amdgcn_logf(x);      // v_log_f32 (log2)
#else
    return __log2f(x);
#endif
}
__device__ __forceinline__ float fast_exp2(float x) {
#if __has_builtin(__builtin_amdgcn_exp2f)
    return __builtin_amdgcn_exp2f(x);     // v_exp_f32 (2^x)
#else
    return exp2f(x);
#endif
}

// inverse sRGB companding on raw x in [-1,1], s=(x+1)/2 folded into FMAs:
//   a  = (s+0.055)/1.055 = fma(x, 0.47393364, 0.52606636)
//   lo = s/12.92         = fma(x, 0.03869969, 0.03869969)
//   hi = a^2.4 = exp2(2.4*log2(a));  select on s>0.04045 <=> x>-0.9191
__device__ __forceinline__ float srgb_expand(float x) {
    float a  = fmaf(x, 0.47393364f, 0.52606636f);
    float hi = fast_exp2(2.4f * fast_log2(a));
    float lo = fmaf(x, 0.03869969f, 0.03869969f);
    return (x > -0.9191f) ? hi : lo;
}

// Lab f(Y); the 116*f-16 affine is folded into caller (|dL| = 116*|df|)
__device__ __forceinline__ float lab_f(float r, float g, float b) {
    float lr = srgb_expand(r);
    float lg = srgb_expand(g);
    float lb = srgb_expand(b);
    float Y  = fmaf(0.2126729f, lr, fmaf(0.7151522f, lg, 0.0721750f * lb));
    float cb = fast_exp2(0.333333333333f * fast_log2(Y));
    float lin = fmaf(7.787f, Y, 16.0f / 116.0f);
    return (Y > 0.008856f) ? cb : lin;
}

__device__ __forceinline__ float group_absdiff(
        float4 gr, float4 gg, float4 gb,
        float4 tr, float4 tg, float4 tb) {
    float s;
    s  = fabsf(lab_f(gr.x, gg.x, gb.x) - lab_f(tr.x, tg.x, tb.x));
    s += fabsf(lab_f(gr.y, gg.y, gb.y) - lab_f(tr.y, tg.y, tb.y));
    s += fabsf(lab_f(gr.z, gg.z, gb.z) - lab_f(tr.z, tg.z, tb.z));
    s += fabsf(lab_f(gr.w, gg.w, gb.w) - lab_f(tr.w, tg.w, tb.w));
    return s;
}

// Inline-asm 16B load: output constraint forces a distinct live VGPR quad per
// load, so the compiler CANNOT serialize/reuse destinations. Volatile asm
// statements keep their mutual program order (loads stay before the waitcnt).
__device__ __forceinline__ float4 gload(const float4* p) {
    float4 r;
    asm volatile("global_load_dwordx4 %0, %1, off" : "=v"(r) : "v"(p));
    return r;
}

__global__ void zero_out_kernel(float* out) {
    if (threadIdx.x == 0) out[0] = 0.0f;
}

__global__ __launch_bounds__(512) void lum_loss_kernel(
        const float* __restrict__ gen,
        const float* __restrict__ tgt,
        float* __restrict__ out) {
    const float4* gp = (const float4*)gen;
    const float4* tp = (const float4*)tgt;

    int t  = blockIdx.x * 512 + threadIdx.x;   // 0 .. HALFG-1
    int ga = t;                                 // group A: first half
    int gb = t + HALFG;                         // group B: second half
    int basea = (ga >> 16) * CHW4 + (ga & 65535);
    int baseb = (gb >> 16) * CHW4 + (gb & 65535);

    // ---- issue all 12 loads back-to-back: group A's 6 first, then B's 6 ----
    float4 agr = gload(gp + basea);
    float4 agg = gload(gp + basea + HW4);
    float4 agb = gload(gp + basea + 2 * HW4);
    float4 atr = gload(tp + basea);
    float4 atg = gload(tp + basea + HW4);
    float4 atb = gload(tp + basea + 2 * HW4);
    float4 bgr = gload(gp + baseb);
    float4 bgg = gload(gp + baseb + HW4);
    float4 bgb = gload(gp + baseb + 2 * HW4);
    float4 btr = gload(tp + baseb);
    float4 btg = gload(tp + baseb + HW4);
    float4 btb = gload(tp + baseb + 2 * HW4);

    // wait for group A only; B's 6 loads remain in flight under A's compute
    asm volatile("s_waitcnt vmcnt(6)" ::: "memory");
    __builtin_amdgcn_sched_barrier(0);   // rule #18: pin compute after waitcnt
    float a = group_absdiff(agr, agg, agb, atr, atg, atb);

    asm volatile("s_waitcnt vmcnt(0)" ::: "memory");
    __builtin_amdgcn_sched_barrier(0);
    a += group_absdiff(bgr, bgg, bgb, btr, btg, btb);
    a *= 116.0f;

    // wave64 reduce
    #pragma unroll
    for (int off = 32; off > 0; off >>= 1)
        a += __shfl_down(a, off, 64);

    __shared__ float smem[8];
    int lane = threadIdx.x & 63;
    int wave = threadIdx.x >> 6;
    if (lane == 0) smem[wave] = a;
    __syncthreads();

    if (threadIdx.x == 0) {
        float s = ((smem[0] + smem[1]) + (smem[2] + smem[3]))
                + ((smem[4] + smem[5]) + (smem[6] + smem[7]));
        atomicAdd(out, s * (1.0f / (float)NPIX));
    }
}

extern "C" void kernel_launch(void* const* d_in, const int* in_sizes, int n_in,
                              void* d_out, int out_size, void* d_ws, size_t ws_size,
                              hipStream_t stream) {
    const float* gen = (const float*)d_in[0];
    const float* tgt = (const float*)d_in[1];
    float* out = (float*)d_out;

    zero_out_kernel<<<1, 64, 0, stream>>>(out);
    // 2,097,152 threads, 2 float4-groups (8 pixels) each = 16,777,216 pixels
    lum_loss_kernel<<<4096, 512, 0, stream>>>(gen, tgt, out);
}